// Round 8
// baseline (288.279 us; speedup 1.0000x reference)
//
#include <hip/hip_runtime.h>
#include <hip/hip_bf16.h>

typedef short s8v __attribute__((ext_vector_type(8)));
typedef float f4v __attribute__((ext_vector_type(4)));

__device__ __forceinline__ float bf2f(short u) {
    unsigned int x = ((unsigned int)(unsigned short)u) << 16;
    return __builtin_bit_cast(float, x);
}
__device__ __forceinline__ short f2bf(float f) {
    unsigned int u = __builtin_bit_cast(unsigned int, f);
    unsigned int r = (u + 0x7FFF + ((u >> 16) & 1)) >> 16;
    return (short)r;
}

// ================= fat kernel: build || transW/bounds/sentinel || GEMM1 =====
// roles by blockIdx: [0,nbBuild) build; [nbBuild,+160) Bt2/Bt3; +3 bounds;
// +1 sentinel-zero of P row n; [nbBuild+164, +256) GEMM1 u1 = x@W1 -> P.
__global__ __launch_bounds__(256)
void k_fat(const int* __restrict__ src, const int* __restrict__ dst, int e,
           int* __restrict__ degp, int* __restrict__ csrcp,
           const float* __restrict__ x, const float* __restrict__ W1,
           const float* __restrict__ W2, const float* __restrict__ W3,
           short* __restrict__ Bt2, short* __restrict__ Bt3,
           const int* __restrict__ batch, int n, int ngr,
           int* __restrict__ gstart, short* __restrict__ P, int nbBuild) {
    int blk = blockIdx.x;
    int tid = threadIdx.x;
    if (blk < nbBuild) {
        // ---- CSR build: padded edge lists, atomic rank ----
        int i = (blk * 256 + tid) * 8;
        if (i + 7 < e) {
            int4 a = *(const int4*)(dst + i);
            int4 b = *(const int4*)(dst + i + 4);
            int4 sa = *(const int4*)(src + i);
            int4 sb = *(const int4*)(src + i + 4);
            int r;
            r = atomicAdd(&degp[a.x << 4], 1); if (r < 64) csrcp[a.x * 64 + r] = sa.x;
            r = atomicAdd(&degp[a.y << 4], 1); if (r < 64) csrcp[a.y * 64 + r] = sa.y;
            r = atomicAdd(&degp[a.z << 4], 1); if (r < 64) csrcp[a.z * 64 + r] = sa.z;
            r = atomicAdd(&degp[a.w << 4], 1); if (r < 64) csrcp[a.w * 64 + r] = sa.w;
            r = atomicAdd(&degp[b.x << 4], 1); if (r < 64) csrcp[b.x * 64 + r] = sb.x;
            r = atomicAdd(&degp[b.y << 4], 1); if (r < 64) csrcp[b.y * 64 + r] = sb.y;
            r = atomicAdd(&degp[b.z << 4], 1); if (r < 64) csrcp[b.z * 64 + r] = sb.z;
            r = atomicAdd(&degp[b.w << 4], 1); if (r < 64) csrcp[b.w * 64 + r] = sb.w;
        } else {
            for (int k = i; k < e; ++k) {
                int d = dst[k];
                int r = atomicAdd(&degp[d << 4], 1);
                if (r < 64) csrcp[d * 64 + r] = src[k];
            }
        }
    } else if (blk < nbBuild + 160) {
        // ---- Bt2[128][256] = W2^T, Bt3[64][128] = W3^T (bf16) ----
        int id = (blk - nbBuild) * 256 + tid;
        if (id < 32768) {
            int c = id >> 8, k = id & 255;
            Bt2[id] = f2bf(W2[k * 128 + c]);
        } else {
            int i2 = id - 32768;
            int c = i2 >> 7, k = i2 & 127;
            Bt3[i2] = f2bf(W3[k * 64 + c]);
        }
    } else if (blk < nbBuild + 163) {
        // ---- graph bounds (sorted batch binary search) ----
        int g = (blk - nbBuild - 160) * 256 + tid;
        if (g > ngr) return;
        if (g == ngr) { gstart[g] = n; return; }
        int lo = 0, hi = n;
        while (lo < hi) { int mid = (lo + hi) >> 1; if (batch[mid] < g) lo = mid + 1; else hi = mid; }
        gstart[g] = lo;
    } else if (blk == nbBuild + 163) {
        // ---- zero sentinel row n of P (256 cols) ----
        P[(size_t)n * 256 + tid] = 0;
    } else {
        // ---- GEMM1: u1[n,256] = bf16(x)[n,128] @ bf16(W1)[128,256] -> P ----
        int gb = blk - (nbBuild + 164);
        const int lane = tid & 63;
        const int gw = (gb * 256 + tid) >> 6;   // 0..1023
        const int colset = gw & 3;              // CT=4
        const int strip0 = gw >> 2;
        const int sstr = 256;                   // 1024/4
        const int l15 = lane & 15, l4 = lane >> 4;
        const int colbase = colset * 64;

        s8v bfr[4][4];
        #pragma unroll
        for (int nt = 0; nt < 4; ++nt) {
            int col = colbase + nt * 16 + l15;
            #pragma unroll
            for (int s = 0; s < 4; ++s) {
                s8v t;
                #pragma unroll
                for (int j = 0; j < 8; ++j)
                    t[j] = f2bf(W1[(s * 32 + l4 * 8 + j) * 256 + col]);
                bfr[nt][s] = t;
            }
        }
        const int nstrips = n >> 4;
        for (int strip = strip0; strip < nstrips; strip += sstr) {
            const float* arow = x + (size_t)(strip * 16 + l15) * 128 + l4 * 8;
            s8v afr[4];
            #pragma unroll
            for (int s = 0; s < 4; ++s) {
                f4v a = *(const f4v*)(arow + s * 32);
                f4v b = *(const f4v*)(arow + s * 32 + 4);
                s8v t;
                #pragma unroll
                for (int j = 0; j < 4; ++j) { t[j] = f2bf(a[j]); t[j + 4] = f2bf(b[j]); }
                afr[s] = t;
            }
            f4v acc[4];
            #pragma unroll
            for (int nt = 0; nt < 4; ++nt) acc[nt] = (f4v){0.f, 0.f, 0.f, 0.f};
            #pragma unroll
            for (int s = 0; s < 4; ++s)
                #pragma unroll
                for (int nt = 0; nt < 4; ++nt)
                    acc[nt] = __builtin_amdgcn_mfma_f32_16x16x32_bf16(afr[s], bfr[nt][s], acc[nt], 0, 0, 0);
            int orow = strip * 16 + l4 * 4;
            #pragma unroll
            for (int nt = 0; nt < 4; ++nt) {
                int col = colbase + nt * 16 + l15;
                #pragma unroll
                for (int r = 0; r < 4; ++r)
                    P[(size_t)(orow + r) * 256 + col] = f2bf(acc[nt][r]);
            }
        }
    }
}

// ---- compact dinv: dinv[i] = rsqrt(deg+1), dinv[n] = 0 (sentinel) ----
__global__ void k_dinv(const int* __restrict__ degp, float* __restrict__ dinv, int n) {
    int i = blockIdx.x * 256 + threadIdx.x;
    if (i < n) dinv[i] = rsqrtf((float)degp[i << 4] + 1.0f);
    else if (i == n) dinv[n] = 0.f;
}

// ---- bf16 MFMA GEMM: C = A @ Bt^T; Bt [N][K] bf16; bias/relu/dinv-scale/zrow ----
template<int K, int NT, int CT, bool BIAS, bool RELU, bool DVS, bool ZROW>
__global__ __launch_bounds__(256)
void k_gemm(const short* __restrict__ A, const short* __restrict__ Bt,
            const float* __restrict__ bias, const float* __restrict__ dinv,
            short* __restrict__ C, int M) {
    constexpr int S = K / 32;
    constexpr int N = NT * 16 * CT;
    if (ZROW && blockIdx.x == 0 && threadIdx.x < N) {
        C[(size_t)M * N + threadIdx.x] = 0;
    }
    const int lane = threadIdx.x & 63;
    const int gw = (blockIdx.x * 256 + threadIdx.x) >> 6;
    const int nw = (gridDim.x * 256) >> 6;
    const int colset = gw % CT;
    const int strip0 = gw / CT;
    const int sstr = nw / CT;
    const int l15 = lane & 15, l4 = lane >> 4;
    const int colbase = colset * (NT * 16);

    s8v bfr[NT][S];
    float bcol[NT];
    #pragma unroll
    for (int nt = 0; nt < NT; ++nt) {
        int col = colbase + nt * 16 + l15;
        if (BIAS) bcol[nt] = bias[col];
        const short* bp = Bt + (size_t)col * K + l4 * 8;
        #pragma unroll
        for (int s = 0; s < S; ++s)
            bfr[nt][s] = *(const s8v*)(bp + s * 32);
    }

    const int nstrips = M >> 4;
    for (int strip = strip0; strip < nstrips; strip += sstr) {
        const short* arow = A + (size_t)(strip * 16 + l15) * K + l4 * 8;
        s8v afr[S];
        #pragma unroll
        for (int s = 0; s < S; ++s)
            afr[s] = *(const s8v*)(arow + s * 32);
        f4v acc[NT];
        #pragma unroll
        for (int nt = 0; nt < NT; ++nt) acc[nt] = (f4v){0.f, 0.f, 0.f, 0.f};
        #pragma unroll
        for (int s = 0; s < S; ++s)
            #pragma unroll
            for (int nt = 0; nt < NT; ++nt)
                acc[nt] = __builtin_amdgcn_mfma_f32_16x16x32_bf16(afr[s], bfr[nt][s], acc[nt], 0, 0, 0);
        int orow = strip * 16 + l4 * 4;
        f4v dvr;
        if (DVS) dvr = *(const f4v*)(dinv + orow);
        #pragma unroll
        for (int nt = 0; nt < NT; ++nt) {
            int col = colbase + nt * 16 + l15;
            #pragma unroll
            for (int r = 0; r < 4; ++r) {
                float v = acc[nt][r];
                if (DVS) v *= dvr[r];
                if (BIAS) v += bcol[nt];
                if (RELU) v = fmaxf(v, 0.f);
                C[(size_t)(orow + r) * N + col] = f2bf(v);
            }
        }
    }
}

// ---- aggregation on padded edge lists.
// EDGEDIV: out = dv*(dv*h[v] + sum ds*h[s]) + b   (h unscaled)
// else   : out = dv*(h[v] + sum h[s]) + b         (h pre-scaled by dinv[src]) ----
template<int D, bool RELU, bool F32OUT, bool BIAS, bool EDGEDIV>
__global__ __launch_bounds__(256)
void k_agg(const short* __restrict__ h, const int* __restrict__ csrcp,
           const int* __restrict__ degp, const float* __restrict__ dinv,
           const float* __restrict__ bias, void* __restrict__ outp, int n) {
    constexpr int T = D / 8;            // lanes per node
    constexpr int GR = (T < 16) ? T : 16;
    int node = (blockIdx.x * 256 + threadIdx.x) / T;
    if (node >= n) return;
    int t = threadIdx.x & (T - 1);
    int c0 = t * 8;
    const short* hp = h + c0;
    float dv = dinv[node];
    float acc[8];
    {
        s8v hv = *(const s8v*)(hp + (size_t)node * D);
        #pragma unroll
        for (int j = 0; j < 8; ++j)
            acc[j] = EDGEDIV ? dv * bf2f(hv[j]) : bf2f(hv[j]);
    }
    int deg = degp[node << 4];
    int nch = (deg + T - 1) / T;
    const int* ep = csrcp + (size_t)node * 64;
    for (int c = 0; c < nch; ++c) {
        int idx = ep[c * T + t];
        #pragma unroll
        for (int jg = 0; jg < T / GR; ++jg) {
            s8v buf[GR];
            float ds[GR];
            #pragma unroll
            for (int j = 0; j < GR; ++j) {
                unsigned s = (unsigned)__shfl(idx, jg * GR + j, T);
                s = s < (unsigned)n ? s : (unsigned)n;   // pad -> zero sentinel row
                if (EDGEDIV) ds[j] = dinv[s];
                buf[j] = *(const s8v*)(hp + (size_t)s * D);
            }
            #pragma unroll
            for (int j = 0; j < GR; ++j) {
                #pragma unroll
                for (int k = 0; k < 8; ++k) {
                    if (EDGEDIV) acc[k] = fmaf(ds[j], bf2f(buf[j][k]), acc[k]);
                    else acc[k] += bf2f(buf[j][k]);
                }
            }
        }
    }

    float out[8];
    #pragma unroll
    for (int j = 0; j < 8; ++j) {
        float b = BIAS ? bias[c0 + j] : 0.f;
        out[j] = dv * acc[j] + b;
        if (RELU) out[j] = fmaxf(out[j], 0.f);
    }
    if (F32OUT) {
        float* op = (float*)outp;
        f4v a = {out[0], out[1], out[2], out[3]}, b2 = {out[4], out[5], out[6], out[7]};
        *(f4v*)(op + (size_t)node * D + c0) = a;
        *(f4v*)(op + (size_t)node * D + c0 + 4) = b2;
    } else {
        short* op = (short*)outp;
        s8v o;
        #pragma unroll
        for (int j = 0; j < 8; ++j) o[j] = f2bf(out[j]);
        *(s8v*)(op + (size_t)node * D + c0) = o;
    }
}

// ---- fused mean-pool + logit + sigmoid + per-graph loss term ----
__global__ void k_poolhead(const float* __restrict__ h3f, const int* __restrict__ gstart,
                           const float* __restrict__ Wl, const float* __restrict__ bl,
                           const int* __restrict__ y, float* __restrict__ out,
                           float* __restrict__ plos) {
    int g = blockIdx.x;
    int j = threadIdx.x;  // 64
    int s = gstart[g], e = gstart[g + 1];
    float acc = 0.f;
    for (int i = s; i < e; ++i) acc += h3f[(size_t)i * 64 + j];
    float cnt = fmaxf((float)(e - s), 1.0f);
    float part = (acc / cnt) * Wl[j];
    #pragma unroll
    for (int d = 32; d > 0; d >>= 1) part += __shfl_down(part, d, 64);
    if (j == 0) {
        float l = part + bl[0];
        out[g] = 1.f / (1.f + expf(-l));
        float t = (float)y[g];
        plos[g] = fmaxf(l, 0.f) - l * t + log1pf(expf(-fabsf(l)));
    }
}

// ---- final loss reduce ----
__global__ void k_loss(const float* __restrict__ plos, float* __restrict__ out) {
    __shared__ float red[512];
    int g = threadIdx.x;
    red[g] = plos[g];
    __syncthreads();
    for (int s = 256; s > 0; s >>= 1) {
        if (g < s) red[g] += red[g + s];
        __syncthreads();
    }
    if (g == 0) out[512] = red[0] / 512.f;
}

extern "C" void kernel_launch(void* const* d_in, const int* in_sizes, int n_in,
                              void* d_out, int out_size, void* d_ws, size_t ws_size,
                              hipStream_t stream) {
    const float* x   = (const float*)d_in[0];
    const int* ei    = (const int*)d_in[1];
    const int* batch = (const int*)d_in[2];
    const int* y     = (const int*)d_in[3];
    const float* W1  = (const float*)d_in[4];
    const float* b1  = (const float*)d_in[5];
    const float* W2  = (const float*)d_in[6];
    const float* b2  = (const float*)d_in[7];
    const float* W3  = (const float*)d_in[8];
    const float* b3  = (const float*)d_in[9];
    const float* Wl  = (const float*)d_in[10];
    const float* bl  = (const float*)d_in[11];

    const int n = in_sizes[2];        // 50000 nodes
    const int e = in_sizes[1] / 2;    // 800000 edges
    const int ngr = 512;
    const int nbBuild = (e / 8 + 255) / 256;   // 391

    char* ws = (char*)d_ws;
    size_t off = 0;
    auto alloc = [&](size_t bytes) {
        char* p = ws + off;
        off = (off + bytes + 255) & ~(size_t)255;
        return p;
    };
    int*   degp   = (int*)alloc((size_t)n * 64);            // 1 counter / 64B line
    int*   csrcp  = (int*)alloc((size_t)n * 64 * 4);        // padded edge lists, cap 64
    short* P      = (short*)alloc((size_t)(n + 1) * 256 * 2);  // u1; later g3'[n+1,64]
    short* Q      = (short*)alloc((size_t)n * 256 * 2);        // h1; later h2[n,128]
    short* R      = (short*)alloc((size_t)(n + 1) * 128 * 2);  // g2'; later h3f fp32
    float* dinv   = (float*)alloc((size_t)(n + 1) * 4);
    int*   gstart = (int*)alloc((size_t)(ngr + 1) * 4);
    short* Bt2    = (short*)alloc((size_t)32768 * 2);
    short* Bt3    = (short*)alloc((size_t)8192 * 2);
    float* plos   = (float*)alloc((size_t)ngr * 4);

    hipMemsetAsync(degp, 0, (size_t)n * 64, stream);
    hipMemsetAsync(csrcp, 0xFF, (size_t)n * 64 * 4, stream);   // -1 sentinels

    // fat: build || Bt2/Bt3 + bounds + P-sentinel || GEMM1 (u1 = x@W1 -> P)
    k_fat<<<nbBuild + 164 + 256, 256, 0, stream>>>(
        ei, ei + e, e, degp, csrcp, x, W1, W2, W3, Bt2, Bt3,
        batch, n, ngr, gstart, P, nbBuild);
    k_dinv<<<(n + 256) / 256, 256, 0, stream>>>(degp, dinv, n);

    // layer 1: h1 = relu(dv*(dv*u1[v] + sum ds*u1[s]) + b1) -> Q [n,256]
    k_agg<256, true, false, true, true><<<(n * 32 + 255) / 256, 256, 0, stream>>>(
        P, csrcp, degp, dinv, b1, Q, n);
    // layer 2: g2' = dv*(h1@W2) -> R [n,128] (+zero row n)
    k_gemm<256, 2, 4, false, false, true, true><<<256, 256, 0, stream>>>(Q, Bt2, nullptr, dinv, R, n);
    //          h2 = relu(dv*(g2'[v]+sum g2'[s]) + b2) -> Q [n,128]
    k_agg<128, true, false, true, false><<<(n * 16 + 255) / 256, 256, 0, stream>>>(
        R, csrcp, degp, dinv, b2, Q, n);
    // layer 3: g3' = dv*(h2@W3) -> P [n+1,64] (+zero row n)
    k_gemm<128, 4, 1, false, false, true, true><<<256, 256, 0, stream>>>(Q, Bt3, nullptr, dinv, P, n);
    //          t3 = dv*(g3'[v]+sum g3'[s]) + b3 -> h3f (fp32, in R)
    float* h3f = (float*)R;
    k_agg<64, false, true, true, false><<<(n * 8 + 255) / 256, 256, 0, stream>>>(
        P, csrcp, degp, dinv, b3, h3f, n);

    // fused mean pool + head; then loss reduce
    k_poolhead<<<ngr, 64, 0, stream>>>(h3f, gstart, Wl, bl, y, (float*)d_out, plos);
    k_loss<<<1, 512, 0, stream>>>(plos, (float*)d_out);
}

// Round 9
// 215.575 us; speedup vs baseline: 1.3373x; 1.3373x over previous
//
#include <hip/hip_runtime.h>
#include <hip/hip_bf16.h>

typedef short s8v __attribute__((ext_vector_type(8)));
typedef float f4v __attribute__((ext_vector_type(4)));

#define EPB 16384          // edges per partition block
#define NBKT 196           // node buckets of 256 (ceil(50000/256))

__device__ __forceinline__ float bf2f(short u) {
    unsigned int x = ((unsigned int)(unsigned short)u) << 16;
    return __builtin_bit_cast(float, x);
}
__device__ __forceinline__ short f2bf(float f) {
    unsigned int u = __builtin_bit_cast(unsigned int, f);
    unsigned int r = (u + 0x7FFF + ((u >> 16) & 1)) >> 16;
    return (short)r;
}

// ---- build A: per-block LDS histogram of dst buckets ----
__global__ __launch_bounds__(256)
void k_hist(const int* __restrict__ dst, int e, int* __restrict__ hist_t, int nbA) {
    __shared__ int h[NBKT];
    int tid = threadIdx.x, blk = blockIdx.x;
    if (tid < NBKT) h[tid] = 0;
    __syncthreads();
    int base = blk * EPB;
    int end = min(base + EPB, e);
    for (int i = base + tid * 4; i < end; i += 1024) {
        if (i + 3 < end) {
            int4 d = *(const int4*)(dst + i);
            atomicAdd(&h[d.x >> 8], 1);
            atomicAdd(&h[d.y >> 8], 1);
            atomicAdd(&h[d.z >> 8], 1);
            atomicAdd(&h[d.w >> 8], 1);
        } else {
            for (int k = i; k < end; ++k) atomicAdd(&h[dst[k] >> 8], 1);
        }
    }
    __syncthreads();
    if (tid < NBKT) hist_t[tid * nbA + blk] = h[tid];
}

// ---- scan pass1 (1024 elems/block, in place) ----
__global__ void k_scan1(int* __restrict__ a, int* __restrict__ bsum, int nelem) {
    __shared__ int ws[4];
    int b = blockIdx.x, tid = threadIdx.x, lane = tid & 63, w = tid >> 6;
    int i0 = b * 1024 + tid * 4;
    int v[4];
    int s = 0;
    #pragma unroll
    for (int k = 0; k < 4; ++k) { v[k] = (i0 + k < nelem) ? a[i0 + k] : 0; s += v[k]; }
    int x = s;
    #pragma unroll
    for (int d = 1; d < 64; d <<= 1) {
        int t2 = __shfl_up(x, d, 64);
        if (lane >= d) x += t2;
    }
    if (lane == 63) ws[w] = x;
    __syncthreads();
    int wo = 0;
    for (int k = 0; k < w; ++k) wo += ws[k];
    int run = wo + x - s;
    #pragma unroll
    for (int k = 0; k < 4; ++k) {
        if (i0 + k < nelem) a[i0 + k] = run;
        run += v[k];
    }
    if (tid == 255) bsum[b] = wo + x;
}

// ---- scan pass2: block sums (nb <= 64) ----
__global__ void k_scan2(int* __restrict__ bsum, int nb) {
    int lane = threadIdx.x;
    int v = (lane < nb) ? bsum[lane] : 0;
    int x = v;
    #pragma unroll
    for (int d = 1; d < 64; d <<= 1) {
        int t2 = __shfl_up(x, d, 64);
        if (lane >= d) x += t2;
    }
    if (lane < nb) bsum[lane] = x - v;
}

// ---- scan pass3: add block offsets (in place) ----
__global__ void k_scan3(int* __restrict__ a, const int* __restrict__ bsum, int nelem) {
    int i = blockIdx.x * 256 + threadIdx.x;
    if (i < nelem) a[i] += bsum[i >> 10];
}

// ---- build C: partition edges into buckets, packed (dstLow8 << 16) | src16 ----
__global__ __launch_bounds__(256)
void k_part(const int* __restrict__ src, const int* __restrict__ dst, int e,
            const int* __restrict__ offs, int nbA, unsigned* __restrict__ parted) {
    __shared__ int cur[NBKT];
    int tid = threadIdx.x, blk = blockIdx.x;
    if (tid < NBKT) cur[tid] = offs[tid * nbA + blk];
    __syncthreads();
    int base = blk * EPB;
    int end = min(base + EPB, e);
    for (int i = base + tid * 4; i < end; i += 1024) {
        if (i + 3 < end) {
            int4 d = *(const int4*)(dst + i);
            int4 s = *(const int4*)(src + i);
            int p;
            p = atomicAdd(&cur[d.x >> 8], 1); parted[p] = (unsigned)s.x | ((unsigned)(d.x & 255) << 16);
            p = atomicAdd(&cur[d.y >> 8], 1); parted[p] = (unsigned)s.y | ((unsigned)(d.y & 255) << 16);
            p = atomicAdd(&cur[d.z >> 8], 1); parted[p] = (unsigned)s.z | ((unsigned)(d.z & 255) << 16);
            p = atomicAdd(&cur[d.w >> 8], 1); parted[p] = (unsigned)s.w | ((unsigned)(d.w & 255) << 16);
        } else {
            for (int k = i; k < end; ++k) {
                int d = dst[k];
                int p = atomicAdd(&cur[d >> 8], 1);
                parted[p] = (unsigned)src[k] | ((unsigned)(d & 255) << 16);
            }
        }
    }
}

// ---- build D: per-bucket padded lists in LDS; emit csrcp, deg, dinv ----
__global__ __launch_bounds__(256)
void k_lists(const unsigned* __restrict__ parted, const int* __restrict__ offs,
             int nbA, int e, int* __restrict__ csrcp, int* __restrict__ deg,
             float* __restrict__ dinv) {
    __shared__ int lists[256 * 64];   // 64 KB
    __shared__ int cnt[256];
    int tid = threadIdx.x, bkt = blockIdx.x;
    #pragma unroll
    for (int k = 0; k < 64; ++k) lists[tid + k * 256] = -1;
    cnt[tid] = 0;
    __syncthreads();
    int base = offs[bkt * nbA];
    int end = (bkt == NBKT - 1) ? e : offs[(bkt + 1) * nbA];
    for (int i = base + tid; i < end; i += 256) {
        unsigned p = parted[i];
        int s = (int)(p & 0xFFFF);
        int dl = (int)((p >> 16) & 0xFF);
        int r = atomicAdd(&cnt[dl], 1);
        if (r < 64) lists[dl * 64 + r] = s;
    }
    __syncthreads();
    size_t gbase = (size_t)bkt * (256 * 64);
    for (int k = tid; k < 256 * 64; k += 256)
        csrcp[gbase + k] = lists[k];
    int c = cnt[tid];
    int node = bkt * 256 + tid;
    deg[node] = min(c, 64);
    dinv[node] = rsqrtf((float)c + 1.0f);
}

// ---- weight transpose (bf16) + graph bounds ----
__global__ void k_transW(const float* __restrict__ W1, const float* __restrict__ W2,
                         const float* __restrict__ W3, short* __restrict__ Bt1,
                         short* __restrict__ Bt2, short* __restrict__ Bt3,
                         const int* __restrict__ batch, int n, int ngr,
                         int* __restrict__ gstart) {
    int blk = blockIdx.x;
    int id = blk * 256 + threadIdx.x;
    if (blk < 288) {
        if (id < 32768) {              // W1: 128x256 -> Bt1[256][128]
            int c = id >> 7, k = id & 127;
            Bt1[id] = f2bf(W1[k * 256 + c]);
        } else if (id < 65536) {       // W2: 256x128 -> Bt2[128][256]
            int i = id - 32768;
            int c = i >> 8, k = i & 255;
            Bt2[i] = f2bf(W2[k * 128 + c]);
        } else if (id < 73728) {       // W3: 128x64 -> Bt3[64][128]
            int i = id - 65536;
            int c = i >> 7, k = i & 127;
            Bt3[i] = f2bf(W3[k * 64 + c]);
        }
    } else {                           // graph bounds via binary search
        int g = (blk - 288) * 256 + threadIdx.x;
        if (g > ngr) return;
        if (g == ngr) { gstart[g] = n; return; }
        int lo = 0, hi = n;
        while (lo < hi) { int mid = (lo + hi) >> 1; if (batch[mid] < g) lo = mid + 1; else hi = mid; }
        gstart[g] = lo;
    }
}

// ---- cast + row-scale: xs[i,:] = bf16(dinv[i] * x[i,:]); row n = zeros ----
__global__ void k_cast_scale(const float* __restrict__ in, const float* __restrict__ dinv,
                             short* __restrict__ outp, int n) {
    int i = blockIdx.x * 256 + threadIdx.x;
    if (i >= (n + 1) * 16) return;
    int row = i >> 4;
    if (row == n) {
        s8v z = {0, 0, 0, 0, 0, 0, 0, 0};
        *(s8v*)(outp + (size_t)i * 8) = z;
        return;
    }
    float dv = dinv[row];
    f4v a = *(const f4v*)(in + (size_t)i * 8);
    f4v b = *(const f4v*)(in + (size_t)i * 8 + 4);
    s8v o;
    #pragma unroll
    for (int j = 0; j < 4; ++j) { o[j] = f2bf(a[j] * dv); o[j + 4] = f2bf(b[j] * dv); }
    *(s8v*)(outp + (size_t)i * 8) = o;
}

// ---- bf16 MFMA GEMM: C = A @ Bt^T; Bt [N][K] bf16; bias/relu/dinv-scale/zrow ----
template<int K, int NT, int CT, bool BIAS, bool RELU, bool DVS, bool ZROW>
__global__ __launch_bounds__(256)
void k_gemm(const short* __restrict__ A, const short* __restrict__ Bt,
            const float* __restrict__ bias, const float* __restrict__ dinv,
            short* __restrict__ C, int M) {
    constexpr int S = K / 32;
    constexpr int N = NT * 16 * CT;
    if (ZROW && blockIdx.x == 0 && threadIdx.x < N) {
        C[(size_t)M * N + threadIdx.x] = 0;
    }
    const int lane = threadIdx.x & 63;
    const int gw = (blockIdx.x * 256 + threadIdx.x) >> 6;
    const int nw = (gridDim.x * 256) >> 6;
    const int colset = gw % CT;
    const int strip0 = gw / CT;
    const int sstr = nw / CT;
    const int l15 = lane & 15, l4 = lane >> 4;
    const int colbase = colset * (NT * 16);

    s8v bfr[NT][S];
    float bcol[NT];
    #pragma unroll
    for (int nt = 0; nt < NT; ++nt) {
        int col = colbase + nt * 16 + l15;
        if (BIAS) bcol[nt] = bias[col];
        const short* bp = Bt + (size_t)col * K + l4 * 8;
        #pragma unroll
        for (int s = 0; s < S; ++s)
            bfr[nt][s] = *(const s8v*)(bp + s * 32);
    }

    const int nstrips = M >> 4;
    for (int strip = strip0; strip < nstrips; strip += sstr) {
        const short* arow = A + (size_t)(strip * 16 + l15) * K + l4 * 8;
        s8v afr[S];
        #pragma unroll
        for (int s = 0; s < S; ++s)
            afr[s] = *(const s8v*)(arow + s * 32);
        f4v acc[NT];
        #pragma unroll
        for (int nt = 0; nt < NT; ++nt) acc[nt] = (f4v){0.f, 0.f, 0.f, 0.f};
        #pragma unroll
        for (int s = 0; s < S; ++s)
            #pragma unroll
            for (int nt = 0; nt < NT; ++nt)
                acc[nt] = __builtin_amdgcn_mfma_f32_16x16x32_bf16(afr[s], bfr[nt][s], acc[nt], 0, 0, 0);
        int orow = strip * 16 + l4 * 4;
        f4v dvr;
        if (DVS) dvr = *(const f4v*)(dinv + orow);
        #pragma unroll
        for (int nt = 0; nt < NT; ++nt) {
            int col = colbase + nt * 16 + l15;
            #pragma unroll
            for (int r = 0; r < 4; ++r) {
                float v = acc[nt][r];
                if (DVS) v *= dvr[r];
                if (BIAS) v += bcol[nt];
                if (RELU) v = fmaxf(v, 0.f);
                C[(size_t)(orow + r) * N + col] = f2bf(v);
            }
        }
    }
}

// ---- aggregation on padded lists (inputs pre-scaled by dinv[src]):
//      out[v] = post(dinv[v] * (h[v] + sum_{s in N(v)} h[s]) + bias) ----
template<int D, bool RELU, bool F32OUT, bool BIAS>
__global__ __launch_bounds__(256)
void k_agg(const short* __restrict__ h, const int* __restrict__ csrcp,
           const int* __restrict__ deg, const float* __restrict__ dinv,
           const float* __restrict__ bias, void* __restrict__ outp, int n) {
    constexpr int T = D / 8;            // lanes per node
    constexpr int GR = (T < 16) ? T : 16;
    int node = (blockIdx.x * 256 + threadIdx.x) / T;
    if (node >= n) return;
    int t = threadIdx.x & (T - 1);
    int c0 = t * 8;
    const short* hp = h + c0;
    float acc[8];
    {
        s8v hv = *(const s8v*)(hp + (size_t)node * D);
        #pragma unroll
        for (int j = 0; j < 8; ++j) acc[j] = bf2f(hv[j]);
    }
    int dg = deg[node];
    int nch = (dg + T - 1) / T;
    const int* ep = csrcp + (size_t)node * 64;
    for (int c = 0; c < nch; ++c) {
        int idx = ep[c * T + t];
        #pragma unroll
        for (int jg = 0; jg < T / GR; ++jg) {
            s8v buf[GR];
            #pragma unroll
            for (int j = 0; j < GR; ++j) {
                unsigned s = (unsigned)__shfl(idx, jg * GR + j, T);
                s = s < (unsigned)n ? s : (unsigned)n;   // -1 pad -> zero sentinel row
                buf[j] = *(const s8v*)(hp + (size_t)s * D);
            }
            #pragma unroll
            for (int j = 0; j < GR; ++j)
                #pragma unroll
                for (int k = 0; k < 8; ++k) acc[k] += bf2f(buf[j][k]);
        }
    }

    float dv = dinv[node];
    float out[8];
    #pragma unroll
    for (int j = 0; j < 8; ++j) {
        float b = BIAS ? bias[c0 + j] : 0.f;
        out[j] = dv * acc[j] + b;
        if (RELU) out[j] = fmaxf(out[j], 0.f);
    }
    if (F32OUT) {
        float* op = (float*)outp;
        f4v a = {out[0], out[1], out[2], out[3]}, b2 = {out[4], out[5], out[6], out[7]};
        *(f4v*)(op + (size_t)node * D + c0) = a;
        *(f4v*)(op + (size_t)node * D + c0 + 4) = b2;
    } else {
        short* op = (short*)outp;
        s8v o;
        #pragma unroll
        for (int j = 0; j < 8; ++j) o[j] = f2bf(out[j]);
        *(s8v*)(op + (size_t)node * D + c0) = o;
    }
}

// ---- fused mean-pool + logit + sigmoid + per-graph loss term ----
__global__ void k_poolhead(const float* __restrict__ h3f, const int* __restrict__ gstart,
                           const float* __restrict__ Wl, const float* __restrict__ bl,
                           const int* __restrict__ y, float* __restrict__ out,
                           float* __restrict__ plos) {
    int g = blockIdx.x;
    int j = threadIdx.x;  // 64
    int s = gstart[g], e = gstart[g + 1];
    float acc = 0.f;
    for (int i = s; i < e; ++i) acc += h3f[(size_t)i * 64 + j];
    float cnt = fmaxf((float)(e - s), 1.0f);
    float part = (acc / cnt) * Wl[j];
    #pragma unroll
    for (int d = 32; d > 0; d >>= 1) part += __shfl_down(part, d, 64);
    if (j == 0) {
        float l = part + bl[0];
        out[g] = 1.f / (1.f + expf(-l));
        float t = (float)y[g];
        plos[g] = fmaxf(l, 0.f) - l * t + log1pf(expf(-fabsf(l)));
    }
}

// ---- final loss reduce ----
__global__ void k_loss(const float* __restrict__ plos, float* __restrict__ out) {
    __shared__ float red[512];
    int g = threadIdx.x;
    red[g] = plos[g];
    __syncthreads();
    for (int s = 256; s > 0; s >>= 1) {
        if (g < s) red[g] += red[g + s];
        __syncthreads();
    }
    if (g == 0) out[512] = red[0] / 512.f;
}

extern "C" void kernel_launch(void* const* d_in, const int* in_sizes, int n_in,
                              void* d_out, int out_size, void* d_ws, size_t ws_size,
                              hipStream_t stream) {
    const float* x   = (const float*)d_in[0];
    const int* ei    = (const int*)d_in[1];
    const int* batch = (const int*)d_in[2];
    const int* y     = (const int*)d_in[3];
    const float* W1  = (const float*)d_in[4];
    const float* b1  = (const float*)d_in[5];
    const float* W2  = (const float*)d_in[6];
    const float* b2  = (const float*)d_in[7];
    const float* W3  = (const float*)d_in[8];
    const float* b3  = (const float*)d_in[9];
    const float* Wl  = (const float*)d_in[10];
    const float* bl  = (const float*)d_in[11];

    const int n = in_sizes[2];        // 50000 nodes
    const int e = in_sizes[1] / 2;    // 800000 edges
    const int ngr = 512;
    const int nbA = (e + EPB - 1) / EPB;        // 49
    const int TE = NBKT * nbA;                  // 9604
    const int nrows = NBKT * 256;               // 50176 padded node rows

    char* ws = (char*)d_ws;
    size_t off = 0;
    auto alloc = [&](size_t bytes) {
        char* p = ws + off;
        off = (off + bytes + 255) & ~(size_t)255;
        return p;
    };
    int*      offs   = (int*)alloc((size_t)TE * 4);
    int*      bsum   = (int*)alloc(64 * 4);
    unsigned* parted = (unsigned*)alloc((size_t)e * 4);
    int*      csrcp  = (int*)alloc((size_t)nrows * 64 * 4);
    int*      deg    = (int*)alloc((size_t)nrows * 4);
    float*    dinv   = (float*)alloc((size_t)nrows * 4);
    short*    xs     = (short*)alloc((size_t)(n + 1) * 128 * 2);  // x', row n zero
    short*    t1     = (short*)alloc((size_t)n * 128 * 2);        // t1; later h2
    short*    h1     = (short*)alloc((size_t)n * 256 * 2);        // h1; later h3f f32
    short*    g2     = (short*)alloc((size_t)(n + 1) * 128 * 2);  // g2'; later g3'
    int*      gstart = (int*)alloc((size_t)(ngr + 1) * 4);
    short*    Bt1    = (short*)alloc((size_t)32768 * 2);
    short*    Bt2    = (short*)alloc((size_t)32768 * 2);
    short*    Bt3    = (short*)alloc((size_t)8192 * 2);
    float*    plos   = (float*)alloc((size_t)ngr * 4);

    // ---- sort-based CSR build (no global atomics, no memsets) ----
    k_hist<<<nbA, 256, 0, stream>>>(ei + e, e, offs, nbA);
    k_scan1<<<(TE + 1023) / 1024, 256, 0, stream>>>(offs, bsum, TE);
    k_scan2<<<1, 64, 0, stream>>>(bsum, (TE + 1023) / 1024);
    k_scan3<<<(TE + 255) / 256, 256, 0, stream>>>(offs, bsum, TE);
    k_part<<<nbA, 256, 0, stream>>>(ei, ei + e, e, offs, nbA, parted);
    k_lists<<<NBKT, 256, 0, stream>>>(parted, offs, nbA, e, csrcp, deg, dinv);

    k_transW<<<291, 256, 0, stream>>>(W1, W2, W3, Bt1, Bt2, Bt3, batch, n, ngr, gstart);

    // x' = bf16(dinv * x) -> xs (row n zeroed)
    k_cast_scale<<<((n + 1) * 16 + 255) / 256, 256, 0, stream>>>(x, dinv, xs, n);

    // layer 1: t1 = dv*(x'[v]+sum x'[s]); h1 = relu(t1@W1+b1)
    k_agg<128, false, false, false><<<(n * 16 + 255) / 256, 256, 0, stream>>>(
        xs, csrcp, deg, dinv, nullptr, t1, n);
    k_gemm<128, 4, 4, true, true, false, false><<<256, 256, 0, stream>>>(t1, Bt1, b1, nullptr, h1, n);
    // layer 2: g2' = dv*(h1@W2) (+zero row n); h2 = relu(dv*(g2'[v]+sum)+b2)
    k_gemm<256, 2, 4, false, false, true, true><<<256, 256, 0, stream>>>(h1, Bt2, nullptr, dinv, g2, n);
    short* h2 = t1;
    k_agg<128, true, false, true><<<(n * 16 + 255) / 256, 256, 0, stream>>>(
        g2, csrcp, deg, dinv, b2, h2, n);
    // layer 3: g3' = dv*(h2@W3) (+zero row n); t3 = dv*(g3'[v]+sum)+b3 (fp32)
    short* g3 = g2;
    k_gemm<128, 4, 1, false, false, true, true><<<256, 256, 0, stream>>>(h2, Bt3, nullptr, dinv, g3, n);
    float* h3f = (float*)h1;
    k_agg<64, false, true, true><<<(n * 8 + 255) / 256, 256, 0, stream>>>(
        g3, csrcp, deg, dinv, b3, h3f, n);

    // fused mean pool + head; then loss reduce
    k_poolhead<<<ngr, 64, 0, stream>>>(h3f, gstart, Wl, bl, y, (float*)d_out, plos);
    k_loss<<<1, 512, 0, stream>>>(plos, (float*)d_out);
}

// Round 10
// 209.428 us; speedup vs baseline: 1.3765x; 1.0293x over previous
//
#include <hip/hip_runtime.h>
#include <hip/hip_bf16.h>

typedef short s8v __attribute__((ext_vector_type(8)));
typedef float f4v __attribute__((ext_vector_type(4)));
typedef unsigned short u16;

#define EPB 16384          // edges per partition block
#define NBKT 196           // node buckets of 256 (ceil(50000/256))

__device__ __forceinline__ float bf2f(short u) {
    unsigned int x = ((unsigned int)(unsigned short)u) << 16;
    return __builtin_bit_cast(float, x);
}
__device__ __forceinline__ short f2bf(float f) {
    unsigned int u = __builtin_bit_cast(unsigned int, f);
    unsigned int r = (u + 0x7FFF + ((u >> 16) & 1)) >> 16;
    return (short)r;
}

// ---- build A: per-block LDS histogram of dst buckets ----
__global__ __launch_bounds__(256)
void k_hist(const int* __restrict__ dst, int e, int* __restrict__ hist_t, int nbA) {
    __shared__ int h[NBKT];
    int tid = threadIdx.x, blk = blockIdx.x;
    if (tid < NBKT) h[tid] = 0;
    __syncthreads();
    int base = blk * EPB;
    int end = min(base + EPB, e);
    for (int i = base + tid * 4; i < end; i += 1024) {
        if (i + 3 < end) {
            int4 d = *(const int4*)(dst + i);
            atomicAdd(&h[d.x >> 8], 1);
            atomicAdd(&h[d.y >> 8], 1);
            atomicAdd(&h[d.z >> 8], 1);
            atomicAdd(&h[d.w >> 8], 1);
        } else {
            for (int k = i; k < end; ++k) atomicAdd(&h[dst[k] >> 8], 1);
        }
    }
    __syncthreads();
    if (tid < NBKT) hist_t[tid * nbA + blk] = h[tid];
}

// ---- scan pass1 (1024 elems/block, in place) ----
__global__ void k_scan1(int* __restrict__ a, int* __restrict__ bsum, int nelem) {
    __shared__ int ws[4];
    int b = blockIdx.x, tid = threadIdx.x, lane = tid & 63, w = tid >> 6;
    int i0 = b * 1024 + tid * 4;
    int v[4];
    int s = 0;
    #pragma unroll
    for (int k = 0; k < 4; ++k) { v[k] = (i0 + k < nelem) ? a[i0 + k] : 0; s += v[k]; }
    int x = s;
    #pragma unroll
    for (int d = 1; d < 64; d <<= 1) {
        int t2 = __shfl_up(x, d, 64);
        if (lane >= d) x += t2;
    }
    if (lane == 63) ws[w] = x;
    __syncthreads();
    int wo = 0;
    for (int k = 0; k < w; ++k) wo += ws[k];
    int run = wo + x - s;
    #pragma unroll
    for (int k = 0; k < 4; ++k) {
        if (i0 + k < nelem) a[i0 + k] = run;
        run += v[k];
    }
    if (tid == 255) bsum[b] = wo + x;
}

// ---- scan pass2: block sums (nb <= 64) ----
__global__ void k_scan2(int* __restrict__ bsum, int nb) {
    int lane = threadIdx.x;
    int v = (lane < nb) ? bsum[lane] : 0;
    int x = v;
    #pragma unroll
    for (int d = 1; d < 64; d <<= 1) {
        int t2 = __shfl_up(x, d, 64);
        if (lane >= d) x += t2;
    }
    if (lane < nb) bsum[lane] = x - v;
}

// ---- scan pass3: add block offsets (in place) ----
__global__ void k_scan3(int* __restrict__ a, const int* __restrict__ bsum, int nelem) {
    int i = blockIdx.x * 256 + threadIdx.x;
    if (i < nelem) a[i] += bsum[i >> 10];
}

// ---- build C: partition edges into buckets, packed (dstLow8 << 16) | src16 ----
__global__ __launch_bounds__(256)
void k_part(const int* __restrict__ src, const int* __restrict__ dst, int e,
            const int* __restrict__ offs, int nbA, unsigned* __restrict__ parted) {
    __shared__ int cur[NBKT];
    int tid = threadIdx.x, blk = blockIdx.x;
    if (tid < NBKT) cur[tid] = offs[tid * nbA + blk];
    __syncthreads();
    int base = blk * EPB;
    int end = min(base + EPB, e);
    for (int i = base + tid * 4; i < end; i += 1024) {
        if (i + 3 < end) {
            int4 d = *(const int4*)(dst + i);
            int4 s = *(const int4*)(src + i);
            int p;
            p = atomicAdd(&cur[d.x >> 8], 1); parted[p] = (unsigned)s.x | ((unsigned)(d.x & 255) << 16);
            p = atomicAdd(&cur[d.y >> 8], 1); parted[p] = (unsigned)s.y | ((unsigned)(d.y & 255) << 16);
            p = atomicAdd(&cur[d.z >> 8], 1); parted[p] = (unsigned)s.z | ((unsigned)(d.z & 255) << 16);
            p = atomicAdd(&cur[d.w >> 8], 1); parted[p] = (unsigned)s.w | ((unsigned)(d.w & 255) << 16);
        } else {
            for (int k = i; k < end; ++k) {
                int d = dst[k];
                int p = atomicAdd(&cur[d >> 8], 1);
                parted[p] = (unsigned)src[k] | ((unsigned)(d & 255) << 16);
            }
        }
    }
}

// ---- build D: per-bucket padded u16 lists in LDS; emit lists, deg, dinv;
//      fused x cast+scale for this bucket's 256 rows ----
__global__ __launch_bounds__(256)
void k_lists(const unsigned* __restrict__ parted, const int* __restrict__ offs,
             int nbA, int e, const float* __restrict__ x, u16* __restrict__ csrcp,
             int* __restrict__ deg, float* __restrict__ dinv,
             short* __restrict__ xs, int n) {
    __shared__ u16 lists[256 * 64];   // 32 KB
    __shared__ int cnt[256];
    int tid = threadIdx.x, bkt = blockIdx.x;
    for (int k = tid; k < 16384; k += 256) lists[k] = 0xFFFF;
    cnt[tid] = 0;
    __syncthreads();
    int base = offs[bkt * nbA];
    int end = (bkt == NBKT - 1) ? e : offs[(bkt + 1) * nbA];
    for (int i = base + tid; i < end; i += 256) {
        unsigned p = parted[i];
        int dl = (int)((p >> 16) & 0xFF);
        int r = atomicAdd(&cnt[dl], 1);
        if (r < 64) lists[dl * 64 + r] = (u16)(p & 0xFFFF);
    }
    __syncthreads();
    // write lists out (32 KB, coalesced 16B units)
    const s8v* lsrc = (const s8v*)lists;
    s8v* ldst = (s8v*)(csrcp + (size_t)bkt * (256 * 64));
    for (int k = tid; k < 2048; k += 256) ldst[k] = lsrc[k];
    // deg & dinv
    int node = bkt * 256 + tid;
    deg[node] = min(cnt[tid], 64);
    dinv[node] = rsqrtf((float)cnt[tid] + 1.0f);
    // fused cast+scale: xs[row,:] = bf16(dinv[row] * x[row,:]) for this bucket
    #pragma unroll 1
    for (int r16 = 0; r16 < 16; ++r16) {
        int local = r16 * 16 + (tid >> 4);
        int row = bkt * 256 + local;
        if (row >= n) continue;
        float dv = rsqrtf((float)cnt[local] + 1.0f);
        int cg = (tid & 15) * 8;
        f4v a = *(const f4v*)(x + (size_t)row * 128 + cg);
        f4v b = *(const f4v*)(x + (size_t)row * 128 + cg + 4);
        s8v o;
        #pragma unroll
        for (int j = 0; j < 4; ++j) { o[j] = f2bf(a[j] * dv); o[j + 4] = f2bf(b[j] * dv); }
        *(s8v*)(xs + (size_t)row * 128 + cg) = o;
    }
}

// ---- weight transpose (bf16) + graph bounds + xs sentinel row ----
__global__ void k_transW(const float* __restrict__ W1, const float* __restrict__ W2,
                         const float* __restrict__ W3, short* __restrict__ Bt1,
                         short* __restrict__ Bt2, short* __restrict__ Bt3,
                         const int* __restrict__ batch, int n, int ngr,
                         int* __restrict__ gstart, short* __restrict__ xs) {
    int blk = blockIdx.x;
    int id = blk * 256 + threadIdx.x;
    if (blk < 288) {
        if (id < 32768) {              // W1: 128x256 -> Bt1[256][128]
            int c = id >> 7, k = id & 127;
            Bt1[id] = f2bf(W1[k * 256 + c]);
        } else if (id < 65536) {       // W2: 256x128 -> Bt2[128][256]
            int i = id - 32768;
            int c = i >> 8, k = i & 255;
            Bt2[i] = f2bf(W2[k * 128 + c]);
        } else if (id < 73728) {       // W3: 128x64 -> Bt3[64][128]
            int i = id - 65536;
            int c = i >> 7, k = i & 127;
            Bt3[i] = f2bf(W3[k * 64 + c]);
        }
    } else if (blk < 291) {            // graph bounds via binary search
        int g = (blk - 288) * 256 + threadIdx.x;
        if (g > ngr) return;
        if (g == ngr) { gstart[g] = n; return; }
        int lo = 0, hi = n;
        while (lo < hi) { int mid = (lo + hi) >> 1; if (batch[mid] < g) lo = mid + 1; else hi = mid; }
        gstart[g] = lo;
    } else {                           // zero sentinel row n of xs
        if (threadIdx.x < 128) xs[(size_t)n * 128 + threadIdx.x] = 0;
    }
}

// ---- bf16 MFMA GEMM with next-strip A prefetch ----
template<int K, int NT, int CT, bool BIAS, bool RELU, bool DVS, bool ZROW>
__global__ __launch_bounds__(256)
void k_gemm(const short* __restrict__ A, const short* __restrict__ Bt,
            const float* __restrict__ bias, const float* __restrict__ dinv,
            short* __restrict__ C, int M) {
    constexpr int S = K / 32;
    constexpr int N = NT * 16 * CT;
    if (ZROW && blockIdx.x == 0 && threadIdx.x < N) {
        C[(size_t)M * N + threadIdx.x] = 0;
    }
    const int lane = threadIdx.x & 63;
    const int gw = (blockIdx.x * 256 + threadIdx.x) >> 6;
    const int nw = (gridDim.x * 256) >> 6;
    const int colset = gw % CT;
    const int strip0 = gw / CT;
    const int sstr = nw / CT;
    const int l15 = lane & 15, l4 = lane >> 4;
    const int colbase = colset * (NT * 16);

    s8v bfr[NT][S];
    float bcol[NT];
    #pragma unroll
    for (int nt = 0; nt < NT; ++nt) {
        int col = colbase + nt * 16 + l15;
        if (BIAS) bcol[nt] = bias[col];
        const short* bp = Bt + (size_t)col * K + l4 * 8;
        #pragma unroll
        for (int s = 0; s < S; ++s)
            bfr[nt][s] = *(const s8v*)(bp + s * 32);
    }

    const int nstrips = M >> 4;
    int strip = strip0;
    if (strip >= nstrips) return;
    s8v cur[S];
    {
        const short* arow = A + (size_t)(strip * 16 + l15) * K + l4 * 8;
        #pragma unroll
        for (int s = 0; s < S; ++s) cur[s] = *(const s8v*)(arow + s * 32);
    }
    while (true) {
        int nstrip = strip + sstr;
        bool has = nstrip < nstrips;
        s8v nxt[S];
        if (has) {
            const short* arow = A + (size_t)(nstrip * 16 + l15) * K + l4 * 8;
            #pragma unroll
            for (int s = 0; s < S; ++s) nxt[s] = *(const s8v*)(arow + s * 32);
        }
        f4v acc[NT];
        #pragma unroll
        for (int nt = 0; nt < NT; ++nt) acc[nt] = (f4v){0.f, 0.f, 0.f, 0.f};
        #pragma unroll
        for (int s = 0; s < S; ++s)
            #pragma unroll
            for (int nt = 0; nt < NT; ++nt)
                acc[nt] = __builtin_amdgcn_mfma_f32_16x16x32_bf16(cur[s], bfr[nt][s], acc[nt], 0, 0, 0);
        int orow = strip * 16 + l4 * 4;
        f4v dvr;
        if (DVS) dvr = *(const f4v*)(dinv + orow);
        #pragma unroll
        for (int nt = 0; nt < NT; ++nt) {
            int col = colbase + nt * 16 + l15;
            #pragma unroll
            for (int r = 0; r < 4; ++r) {
                float v = acc[nt][r];
                if (DVS) v *= dvr[r];
                if (BIAS) v += bcol[nt];
                if (RELU) v = fmaxf(v, 0.f);
                C[(size_t)(orow + r) * N + col] = f2bf(v);
            }
        }
        if (!has) break;
        strip = nstrip;
        #pragma unroll
        for (int s = 0; s < S; ++s) cur[s] = nxt[s];
    }
}

// ---- aggregation on padded u16 lists (inputs pre-scaled by dinv[src]):
//      out[v] = post(dinv[v] * (h[v] + sum_{s in N(v)} h[s]) + bias) ----
template<int D, bool RELU, bool F32OUT, bool BIAS>
__global__ __launch_bounds__(256, 2)
void k_agg(const short* __restrict__ h, const u16* __restrict__ csrcp,
           const int* __restrict__ deg, const float* __restrict__ dinv,
           const float* __restrict__ bias, void* __restrict__ outp, int n) {
    constexpr int T = D / 8;            // lanes per node
    constexpr int GR = (T < 16) ? T : 16;
    int node = (blockIdx.x * 256 + threadIdx.x) / T;
    if (node >= n) return;
    int t = threadIdx.x & (T - 1);
    int c0 = t * 8;
    const short* hp = h + c0;
    float acc[8];
    {
        s8v hv = *(const s8v*)(hp + (size_t)node * D);
        #pragma unroll
        for (int j = 0; j < 8; ++j) acc[j] = bf2f(hv[j]);
    }
    int dg = deg[node];
    int nch = (dg + T - 1) / T;
    const u16* ep = csrcp + (size_t)node * 64;
    for (int c = 0; c < nch; ++c) {
        int idx = (int)ep[c * T + t];
        #pragma unroll
        for (int jg = 0; jg < T / GR; ++jg) {
            s8v buf[GR];
            #pragma unroll
            for (int j = 0; j < GR; ++j) {
                unsigned s = (unsigned)__shfl(idx, jg * GR + j, T);
                s = s < (unsigned)n ? s : (unsigned)n;   // 0xFFFF pad -> zero row n
                buf[j] = *(const s8v*)(hp + (size_t)s * D);
            }
            #pragma unroll
            for (int j = 0; j < GR; ++j)
                #pragma unroll
                for (int k = 0; k < 8; ++k) acc[k] += bf2f(buf[j][k]);
        }
    }

    float dv = dinv[node];
    float out[8];
    #pragma unroll
    for (int j = 0; j < 8; ++j) {
        float b = BIAS ? bias[c0 + j] : 0.f;
        out[j] = dv * acc[j] + b;
        if (RELU) out[j] = fmaxf(out[j], 0.f);
    }
    if (F32OUT) {
        float* op = (float*)outp;
        f4v a = {out[0], out[1], out[2], out[3]}, b2 = {out[4], out[5], out[6], out[7]};
        *(f4v*)(op + (size_t)node * D + c0) = a;
        *(f4v*)(op + (size_t)node * D + c0 + 4) = b2;
    } else {
        short* op = (short*)outp;
        s8v o;
        #pragma unroll
        for (int j = 0; j < 8; ++j) o[j] = f2bf(out[j]);
        *(s8v*)(op + (size_t)node * D + c0) = o;
    }
}

// ---- fused mean-pool + logit + sigmoid + per-graph loss term ----
__global__ void k_poolhead(const float* __restrict__ h3f, const int* __restrict__ gstart,
                           const float* __restrict__ Wl, const float* __restrict__ bl,
                           const int* __restrict__ y, float* __restrict__ out,
                           float* __restrict__ plos) {
    int g = blockIdx.x;
    int j = threadIdx.x;  // 64
    int s = gstart[g], e = gstart[g + 1];
    float acc = 0.f;
    for (int i = s; i < e; ++i) acc += h3f[(size_t)i * 64 + j];
    float cnt = fmaxf((float)(e - s), 1.0f);
    float part = (acc / cnt) * Wl[j];
    #pragma unroll
    for (int d = 32; d > 0; d >>= 1) part += __shfl_down(part, d, 64);
    if (j == 0) {
        float l = part + bl[0];
        out[g] = 1.f / (1.f + expf(-l));
        float t = (float)y[g];
        plos[g] = fmaxf(l, 0.f) - l * t + log1pf(expf(-fabsf(l)));
    }
}

// ---- final loss reduce ----
__global__ void k_loss(const float* __restrict__ plos, float* __restrict__ out) {
    __shared__ float red[512];
    int g = threadIdx.x;
    red[g] = plos[g];
    __syncthreads();
    for (int s = 256; s > 0; s >>= 1) {
        if (g < s) red[g] += red[g + s];
        __syncthreads();
    }
    if (g == 0) out[512] = red[0] / 512.f;
}

extern "C" void kernel_launch(void* const* d_in, const int* in_sizes, int n_in,
                              void* d_out, int out_size, void* d_ws, size_t ws_size,
                              hipStream_t stream) {
    const float* x   = (const float*)d_in[0];
    const int* ei    = (const int*)d_in[1];
    const int* batch = (const int*)d_in[2];
    const int* y     = (const int*)d_in[3];
    const float* W1  = (const float*)d_in[4];
    const float* b1  = (const float*)d_in[5];
    const float* W2  = (const float*)d_in[6];
    const float* b2  = (const float*)d_in[7];
    const float* W3  = (const float*)d_in[8];
    const float* b3  = (const float*)d_in[9];
    const float* Wl  = (const float*)d_in[10];
    const float* bl  = (const float*)d_in[11];

    const int n = in_sizes[2];        // 50000 nodes
    const int e = in_sizes[1] / 2;    // 800000 edges
    const int ngr = 512;
    const int nbA = (e + EPB - 1) / EPB;        // 49
    const int TE = NBKT * nbA;                  // 9604
    const int nrows = NBKT * 256;               // 50176 padded node rows

    char* ws = (char*)d_ws;
    size_t off = 0;
    auto alloc = [&](size_t bytes) {
        char* p = ws + off;
        off = (off + bytes + 255) & ~(size_t)255;
        return p;
    };
    int*      offs   = (int*)alloc((size_t)TE * 4);
    int*      bsum   = (int*)alloc(64 * 4);
    unsigned* parted = (unsigned*)alloc((size_t)e * 4);
    u16*      csrcp  = (u16*)alloc((size_t)nrows * 64 * 2);
    int*      deg    = (int*)alloc((size_t)nrows * 4);
    float*    dinv   = (float*)alloc((size_t)nrows * 4);
    short*    xs     = (short*)alloc((size_t)(n + 1) * 128 * 2);  // x', row n zero
    short*    t1     = (short*)alloc((size_t)n * 128 * 2);        // t1; later h2
    short*    h1     = (short*)alloc((size_t)n * 256 * 2);        // h1; later h3f f32
    short*    g2     = (short*)alloc((size_t)(n + 1) * 128 * 2);  // g2'; later g3'
    int*      gstart = (int*)alloc((size_t)(ngr + 1) * 4);
    short*    Bt1    = (short*)alloc((size_t)32768 * 2);
    short*    Bt2    = (short*)alloc((size_t)32768 * 2);
    short*    Bt3    = (short*)alloc((size_t)8192 * 2);
    float*    plos   = (float*)alloc((size_t)ngr * 4);

    // ---- sort-based CSR build (no global atomics, no memsets) ----
    k_hist<<<nbA, 256, 0, stream>>>(ei + e, e, offs, nbA);
    k_scan1<<<(TE + 1023) / 1024, 256, 0, stream>>>(offs, bsum, TE);
    k_scan2<<<1, 64, 0, stream>>>(bsum, (TE + 1023) / 1024);
    k_scan3<<<(TE + 255) / 256, 256, 0, stream>>>(offs, bsum, TE);
    k_part<<<nbA, 256, 0, stream>>>(ei, ei + e, e, offs, nbA, parted);
    k_lists<<<NBKT, 256, 0, stream>>>(parted, offs, nbA, e, x, csrcp, deg, dinv, xs, n);

    k_transW<<<292, 256, 0, stream>>>(W1, W2, W3, Bt1, Bt2, Bt3, batch, n, ngr, gstart, xs);

    // layer 1: t1 = dv*(x'[v]+sum x'[s]); h1 = relu(t1@W1+b1)
    k_agg<128, false, false, false><<<(n * 16 + 255) / 256, 256, 0, stream>>>(
        xs, csrcp, deg, dinv, nullptr, t1, n);
    k_gemm<128, 4, 4, true, true, false, false><<<256, 256, 0, stream>>>(t1, Bt1, b1, nullptr, h1, n);
    // layer 2: g2' = dv*(h1@W2) (+zero row n); h2 = relu(dv*(g2'[v]+sum)+b2)
    k_gemm<256, 2, 4, false, false, true, true><<<256, 256, 0, stream>>>(h1, Bt2, nullptr, dinv, g2, n);
    short* h2 = t1;
    k_agg<128, true, false, true><<<(n * 16 + 255) / 256, 256, 0, stream>>>(
        g2, csrcp, deg, dinv, b2, h2, n);
    // layer 3: g3' = dv*(h2@W3) (+zero row n); t3 = dv*(g3'[v]+sum)+b3 (fp32)
    short* g3 = g2;
    k_gemm<128, 4, 1, false, false, true, true><<<256, 256, 0, stream>>>(h2, Bt3, nullptr, dinv, g3, n);
    float* h3f = (float*)h1;
    k_agg<64, false, true, true><<<(n * 8 + 255) / 256, 256, 0, stream>>>(
        g3, csrcp, deg, dinv, b3, h3f, n);

    // fused mean pool + head; then loss reduce
    k_poolhead<<<ngr, 64, 0, stream>>>(h3f, gstart, Wl, bl, y, (float*)d_out, plos);
    k_loss<<<1, 512, 0, stream>>>(plos, (float*)d_out);
}